// Round 7
// baseline (280.706 us; speedup 1.0000x reference)
//
#include <hip/hip_runtime.h>
#include <math.h>

#define NN 10000
#define BB 4
#define EE 160000
#define CC 64
#define CE 16

// ---- workspace layout (bytes) ----
static constexpr size_t OFF_XPA    = 0;          // float[NN*BB*CC]
static constexpr size_t OFF_XPB    = 10240000;   // float[NN*BB*CC]
static constexpr size_t OFF_SA     = 20480000;   // float[NN*BB]
static constexpr size_t OFF_SB     = 20640000;   // float[NN*BB]
static constexpr size_t OFF_VECS   = 20800000;   // float[288]
static constexpr size_t OFF_COUNTS = 20801280;   // int[NN]
static constexpr size_t OFF_CURSOR = 20841280;   // int[NN]
static constexpr size_t OFF_OFFS   = 20881280;   // int[NN+1]
static constexpr size_t OFF_RECS   = 20921344;   // int2[EE]   (1.28 MB)
static constexpr size_t OFF_ATT    = 22201344;   // float4[EE] (2.56 MB)
static constexpr size_t OFF_SE12   = 24761344;   // float2[EE] (1.28 MB)
static constexpr size_t OFF_ORDER  = 26041344;   // int[NN]    -> total ~26.1 MB

__device__ __forceinline__ float sigmoidf_(float x) {
    // v_rcp_f32 (~1ulp) instead of IEEE divide; validated absmax-identical r1-r6
    return __builtin_amdgcn_rcpf(1.0f + __expf(-x));
}

// broadcast lane `l` (compile-time) of v to all lanes via v_readlane (SGPR path,
// on the VALU pipes -- NOT the LDS pipe)
__device__ __forceinline__ float bcast_(float v, int l) {
    return __uint_as_float(__builtin_amdgcn_readlane(__float_as_uint(v), l));
}

// histogram of dst + (block 0) fold q@aw_q, k@aw_k, w_e@aw_e for both layers
__global__ void hist_vecs_kernel(const int* __restrict__ ei, int* __restrict__ counts,
                                 const float* __restrict__ q1, const float* __restrict__ k1,
                                 const float* __restrict__ aw1, const float* __restrict__ we1,
                                 const float* __restrict__ q2, const float* __restrict__ k2,
                                 const float* __restrict__ aw2, const float* __restrict__ we2,
                                 float* __restrict__ vecs) {
    int e = blockIdx.x * blockDim.x + threadIdx.x;
    if (e < EE) atomicAdd(&counts[ei[EE + e]], 1);
    if (blockIdx.x == 0) {
        int t = threadIdx.x;
        if (t < 64) {
            float a = 0.f, b = 0.f, c = 0.f, d = 0.f;
            for (int j = 0; j < 64; ++j) {
                a = fmaf(q1[t * 64 + j], aw1[j], a);
                b = fmaf(k1[t * 64 + j], aw1[64 + j], b);
                c = fmaf(q2[t * 64 + j], aw2[j], c);
                d = fmaf(k2[t * 64 + j], aw2[64 + j], d);
            }
            vecs[t] = a; vecs[64 + t] = b; vecs[144 + t] = c; vecs[208 + t] = d;
        }
        if (t < 16) {
            float a = 0.f, b = 0.f;
            for (int j = 0; j < 64; ++j) {
                a = fmaf(we1[t * 64 + j], aw1[128 + j], a);
                b = fmaf(we2[t * 64 + j], aw2[128 + j], b);
            }
            vecs[128 + t] = a; vecs[272 + t] = b;
        }
    }
}

// single-block: exclusive scan of counts -> offs, then degree-descending
// permutation -> order[].  ZERO atomics: r6's version did ~20000 LDS atomicAdds
// onto ~30 hot bins (Poisson(16) degrees) -- ~64-way same-address serialization
// on one CU.  Replaced by 6-ballot value-match (rank/count per wave) + per-wave
// private histogram rows + wave-0 cross-wave prefix + running bin cursors.
__global__ __launch_bounds__(1024) void scan_order_kernel(const int* __restrict__ counts,
                                                          int* __restrict__ offs,
                                                          int* __restrict__ order) {
    __shared__ int wsum[16];
    __shared__ int whist[16][64];   // per-wave degree histogram (deg capped at 63)
    __shared__ int wrnd[16][64];    // per-round per-wave bases
    __shared__ int binbase[64];     // start position of each bin (descending order)
    __shared__ int ocur[64];        // emitted count per bin (across rounds)
    int t = threadIdx.x, lane = t & 63, wid = t >> 6;

    // load degrees (10 nodes per thread)
    int v[10];
    int s = 0;
    #pragma unroll
    for (int j = 0; j < 10; ++j) {
        int i = t * 10 + j;
        v[j] = (i < NN) ? counts[i] : 0;
        s += v[j];
    }
    whist[wid][lane] = 0;
    if (t < 64) ocur[t] = 0;

    // ---- phase 1: exclusive scan -> offs ----
    int ps = s;
    #pragma unroll
    for (int off = 1; off < 64; off <<= 1) {
        int u = __shfl_up(ps, off, 64);
        if (lane >= off) ps += u;
    }
    if (lane == 63) wsum[wid] = ps;
    __syncthreads();
    int wbase = 0;
    for (int w = 0; w < wid; ++w) wbase += wsum[w];
    int tb = wbase + ps - s;  // exclusive prefix
    #pragma unroll
    for (int j = 0; j < 10; ++j) {
        int i = t * 10 + j;
        if (i < NN) offs[i] = tb;
        tb += v[j];
    }
    if (t == 1023) offs[NN] = tb;

    // ---- pass A: degree histogram via ballot match (no atomics) ----
    #pragma unroll
    for (int j = 0; j < 10; ++j) {
        int i = t * 10 + j;
        bool valid = (i < NN);
        int d = v[j] > 63 ? 63 : v[j];
        unsigned long long m = __ballot(valid);
        #pragma unroll
        for (int b = 0; b < 6; ++b) {
            unsigned long long bb = __ballot((d >> b) & 1);
            m &= ((d >> b) & 1) ? bb : ~bb;
        }
        if (valid) {
            int rank = __popcll(m & ((1ull << lane) - 1ull));
            if (rank == 0) whist[wid][d] += __popcll(m);  // leaders: distinct d, wave-private row
        }
    }
    __syncthreads();
    // total hist + descending suffix -> binbase  (wave 0, lane = degree)
    if (t < 64) {
        int tot = 0;
        #pragma unroll
        for (int w = 0; w < 16; ++w) tot += whist[w][t];
        int x = tot;
        #pragma unroll
        for (int off = 1; off < 64; off <<= 1) {
            int u = __shfl_up(x, off, 64);
            if (lane >= off) x += u;
        }
        int total = __shfl(x, 63, 64);
        binbase[t] = total - x;   // #nodes with degree > t
    }
    __syncthreads();

    // ---- pass B: assign positions (deterministic ranks, running cursors) ----
    for (int j = 0; j < 10; ++j) {
        wrnd[wid][lane] = 0;
        __syncthreads();
        int i = t * 10 + j;
        bool valid = (i < NN);
        int d = v[j] > 63 ? 63 : v[j];
        unsigned long long m = __ballot(valid);
        #pragma unroll
        for (int b = 0; b < 6; ++b) {
            unsigned long long bb = __ballot((d >> b) & 1);
            m &= ((d >> b) & 1) ? bb : ~bb;
        }
        int rank = __popcll(m & ((1ull << lane) - 1ull));
        if (valid && rank == 0) wrnd[wid][d] = __popcll(m);
        __syncthreads();
        if (t < 64) {   // cross-wave prefix for this round + cursor update
            int run = ocur[t];
            #pragma unroll
            for (int w = 0; w < 16; ++w) {
                int c = wrnd[w][t];
                wrnd[w][t] = run;
                run += c;
            }
            ocur[t] = run;
        }
        __syncthreads();
        if (valid) order[binbase[d] + wrnd[wid][d] + rank] = i;
        __syncthreads();
    }
}

// CSR scatter; also fold attr·(w_e@aw_e)+ab per edge for both layers -> se12[e]
__global__ __launch_bounds__(256) void scatter_kernel(
    const int* __restrict__ ei, const int* __restrict__ offs,
    int* __restrict__ cursor, const float* __restrict__ attr,
    const float* __restrict__ vecs, const float* __restrict__ ab1,
    const float* __restrict__ ab2, int2* __restrict__ recs,
    float2* __restrict__ se12) {
    int e = blockIdx.x * blockDim.x + threadIdx.x;
    if (e >= EE) return;
    int s = ei[e], d = ei[EE + e];
    const float4* ap = (const float4*)(attr + (size_t)e * CE);
    float4 a0 = ap[0], a1 = ap[1], a2 = ap[2], a3 = ap[3];
    const float* v1 = vecs + 128;
    const float* v2 = vecs + 272;
    float s1 = ab1[0], s2 = ab2[0];
    s1 = fmaf(a0.x, v1[0], s1);  s1 = fmaf(a0.y, v1[1], s1);
    s1 = fmaf(a0.z, v1[2], s1);  s1 = fmaf(a0.w, v1[3], s1);
    s1 = fmaf(a1.x, v1[4], s1);  s1 = fmaf(a1.y, v1[5], s1);
    s1 = fmaf(a1.z, v1[6], s1);  s1 = fmaf(a1.w, v1[7], s1);
    s1 = fmaf(a2.x, v1[8], s1);  s1 = fmaf(a2.y, v1[9], s1);
    s1 = fmaf(a2.z, v1[10], s1); s1 = fmaf(a2.w, v1[11], s1);
    s1 = fmaf(a3.x, v1[12], s1); s1 = fmaf(a3.y, v1[13], s1);
    s1 = fmaf(a3.z, v1[14], s1); s1 = fmaf(a3.w, v1[15], s1);
    s2 = fmaf(a0.x, v2[0], s2);  s2 = fmaf(a0.y, v2[1], s2);
    s2 = fmaf(a0.z, v2[2], s2);  s2 = fmaf(a0.w, v2[3], s2);
    s2 = fmaf(a1.x, v2[4], s2);  s2 = fmaf(a1.y, v2[5], s2);
    s2 = fmaf(a1.z, v2[6], s2);  s2 = fmaf(a1.w, v2[7], s2);
    s2 = fmaf(a2.x, v2[8], s2);  s2 = fmaf(a2.y, v2[9], s2);
    s2 = fmaf(a2.z, v2[10], s2); s2 = fmaf(a2.w, v2[11], s2);
    s2 = fmaf(a3.x, v2[12], s2); s2 = fmaf(a3.y, v2[13], s2);
    s2 = fmaf(a3.z, v2[14], s2); s2 = fmaf(a3.w, v2[15], s2);
    int p = atomicAdd(&cursor[d], 1);
    recs[offs[d] + p] = make_int2(s, e);
    se12[e] = make_float2(s1, s2);
}

// xp = x @ w_n ; sa = xp@qa ; sb = xp@ka.  One wave per node, 4 nodes/block.
// ZERO LDS, ZERO barrier (r6-validated: -26 us non-conv): wave loads node row as
// one float4/lane; x[b][ci] broadcast via v_readlane at compile-time lane index.
__global__ __launch_bounds__(256) void node_prep_kernel(
    const float* __restrict__ x, const float* __restrict__ w_n,
    const float* __restrict__ qa, const float* __restrict__ ka,
    float* __restrict__ xp, float* __restrict__ sa, float* __restrict__ sb) {
    int t = threadIdx.x, wave = t >> 6, lane = t & 63;
    int node = blockIdx.x * 4 + wave;
    float4 xv = ((const float4*)(x + (size_t)node * BB * CC))[lane];
    float acc0 = 0.f, acc1 = 0.f, acc2 = 0.f, acc3 = 0.f;
    #pragma unroll
    for (int ci = 0; ci < 64; ++ci) {
        float w = w_n[ci * 64 + lane];                 // coalesced column of w_n
        float c0 = ((ci & 3) == 0) ? xv.x : ((ci & 3) == 1) ? xv.y
                 : ((ci & 3) == 2) ? xv.z : xv.w;
        int src = ci >> 2;
        acc0 = fmaf(bcast_(c0, (0 << 4) | src), w, acc0);
        acc1 = fmaf(bcast_(c0, (1 << 4) | src), w, acc1);
        acc2 = fmaf(bcast_(c0, (2 << 4) | src), w, acc2);
        acc3 = fmaf(bcast_(c0, (3 << 4) | src), w, acc3);
    }
    size_t obase = (size_t)node * BB * CC + lane;
    xp[obase] = acc0;
    xp[obase + 64] = acc1;
    xp[obase + 128] = acc2;
    xp[obase + 192] = acc3;
    float qv = qa[lane], kv = ka[lane];
    float ra0 = acc0 * qv, ra1 = acc1 * qv, ra2 = acc2 * qv, ra3 = acc3 * qv;
    float rb0 = acc0 * kv, rb1 = acc1 * kv, rb2 = acc2 * kv, rb3 = acc3 * kv;
    #pragma unroll
    for (int off = 32; off >= 1; off >>= 1) {
        ra0 += __shfl_xor(ra0, off, 64); ra1 += __shfl_xor(ra1, off, 64);
        ra2 += __shfl_xor(ra2, off, 64); ra3 += __shfl_xor(ra3, off, 64);
        rb0 += __shfl_xor(rb0, off, 64); rb1 += __shfl_xor(rb1, off, 64);
        rb2 += __shfl_xor(rb2, off, 64); rb3 += __shfl_xor(rb3, off, 64);
    }
    if (lane == 0) {
        sa[node * BB + 0] = ra0; sa[node * BB + 1] = ra1;
        sa[node * BB + 2] = ra2; sa[node * BB + 3] = ra3;
        sb[node * BB + 0] = rb0; sb[node * BB + 1] = rb1;
        sb[node * BB + 2] = rb2; sb[node * BB + 3] = rb3;
    }
}

// per-edge attention scalar: att4[e] = sigmoid(sa[src] + sb[dst] + se12[e])
__global__ __launch_bounds__(256) void att_kernel(
    const int* __restrict__ ei, const float2* __restrict__ se12,
    const float* __restrict__ sa, const float* __restrict__ sb,
    float4* __restrict__ att, int sel) {
    int e = blockIdx.x * blockDim.x + threadIdx.x;
    if (e >= EE) return;
    int s = ei[e], d = ei[EE + e];
    float2 se2 = se12[e];
    float se = sel ? se2.y : se2.x;
    float4 sas = *(const float4*)(sa + (size_t)s * BB);
    float4 sbn = *(const float4*)(sb + (size_t)d * BB);
    float4 r;
    r.x = sigmoidf_(sas.x + sbn.x + se);
    r.y = sigmoidf_(sas.y + sbn.y + se);
    r.z = sigmoidf_(sas.z + sbn.z + se);
    r.w = sigmoidf_(sas.w + sbn.w + se);
    att[e] = r;
}

// Per-node segment-max aggregation + output linear + residual + leaky_relu.
// EXACT r5 form (proven 54.7 us): one wave per node (lane = channel), LPT order,
// simple 1-ahead rec prefetch (depth-2 pipelining regressed twice: r1, r6),
// readlane epilogue (zero LDS).
__global__ __launch_bounds__(256) void conv_out_kernel(
    const float* __restrict__ xp,      // [NN,BB,CC]
    const int2* __restrict__ recs,     // [EE] {src, e}
    const int* __restrict__ offs,      // [NN+1]
    const float* __restrict__ attr,    // [EE,CE]
    const float* __restrict__ w_e,     // [CE,CC]
    const float4* __restrict__ att,    // [EE]
    const float* __restrict__ ow,      // [2*CC,CC]
    const float* __restrict__ ob,      // [CC]
    const int* __restrict__ order,     // [NN] degree-descending node ids
    float* __restrict__ out) {         // [NN,BB,CC]
    int t = threadIdx.x;
    int wave = t >> 6, lane = t & 63;
    int node = order[blockIdx.x * 4 + wave];

    float wec[CE];
    #pragma unroll
    for (int j = 0; j < CE; ++j) wec[j] = w_e[j * CC + lane];

    const float* xn = xp + (size_t)node * BB * CC + lane;
    float xn0 = xn[0], xn1 = xn[64], xn2 = xn[128], xn3 = xn[192];

    int o0 = offs[node], o1 = offs[node + 1];
    float m0 = -INFINITY, m1 = -INFINITY, m2 = -INFINITY, m3 = -INFINITY;

    int i = o0;
    int2 rec = (i < o1) ? recs[i] : make_int2(0, 0);
    while (i < o1) {
        int2 cur = rec;
        ++i;
        if (i < o1) rec = recs[i];  // prefetch next
        int s = cur.x, e = cur.y;
        float4 at = att[e];
        const float4* ap = (const float4*)(attr + (size_t)e * CE);
        float4 a0 = ap[0], a1 = ap[1], a2 = ap[2], a3 = ap[3];
        float g = 0.f;
        g = fmaf(a0.x, wec[0], g);  g = fmaf(a0.y, wec[1], g);
        g = fmaf(a0.z, wec[2], g);  g = fmaf(a0.w, wec[3], g);
        g = fmaf(a1.x, wec[4], g);  g = fmaf(a1.y, wec[5], g);
        g = fmaf(a1.z, wec[6], g);  g = fmaf(a1.w, wec[7], g);
        g = fmaf(a2.x, wec[8], g);  g = fmaf(a2.y, wec[9], g);
        g = fmaf(a2.z, wec[10], g); g = fmaf(a2.w, wec[11], g);
        g = fmaf(a3.x, wec[12], g); g = fmaf(a3.y, wec[13], g);
        g = fmaf(a3.z, wec[14], g); g = fmaf(a3.w, wec[15], g);
        g = sigmoidf_(g);
        const float* xs = xp + (size_t)s * BB * CC + lane;
        float x0 = xs[0], x1 = xs[64], x2 = xs[128], x3 = xs[192];
        m0 = fmaxf(m0, at.x * x0 * g);
        m1 = fmaxf(m1, at.y * x1 * g);
        m2 = fmaxf(m2, at.z * x2 * g);
        m3 = fmaxf(m3, at.w * x3 * g);
    }
    // empty segments -> 0
    m0 = (m0 == -INFINITY) ? 0.f : m0;
    m1 = (m1 == -INFINITY) ? 0.f : m1;
    m2 = (m2 == -INFINITY) ? 0.f : m2;
    m3 = (m3 == -INFINITY) ? 0.f : m3;

    // ---- epilogue: out = xp + concat([xp, aggr]) @ ow + ob, leaky_relu ----
    // lane = output channel; per ci: 2 coalesced ow loads + 8 readlane + 8 FMA
    float o0f = 0.f, o1f = 0.f, o2f = 0.f, o3f = 0.f;
    #pragma unroll
    for (int ci = 0; ci < 64; ++ci) {
        float wa = ow[ci * 64 + lane];         // coalesced, L1/L2-resident
        float wb = ow[(64 + ci) * 64 + lane];
        o0f = fmaf(bcast_(xn0, ci), wa, o0f);
        o1f = fmaf(bcast_(xn1, ci), wa, o1f);
        o2f = fmaf(bcast_(xn2, ci), wa, o2f);
        o3f = fmaf(bcast_(xn3, ci), wa, o3f);
        o0f = fmaf(bcast_(m0, ci), wb, o0f);
        o1f = fmaf(bcast_(m1, ci), wb, o1f);
        o2f = fmaf(bcast_(m2, ci), wb, o2f);
        o3f = fmaf(bcast_(m3, ci), wb, o3f);
    }
    float obv = ob[lane];
    float r0 = xn0 + o0f + obv;
    float r1 = xn1 + o1f + obv;
    float r2 = xn2 + o2f + obv;
    float r3 = xn3 + o3f + obv;
    r0 = (r0 > 0.f) ? r0 : 0.01f * r0;
    r1 = (r1 > 0.f) ? r1 : 0.01f * r1;
    r2 = (r2 > 0.f) ? r2 : 0.01f * r2;
    r3 = (r3 > 0.f) ? r3 : 0.01f * r3;
    float* op = out + (size_t)node * BB * CC + lane;
    op[0] = r0; op[64] = r1; op[128] = r2; op[192] = r3;
}

extern "C" void kernel_launch(void* const* d_in, const int* in_sizes, int n_in,
                              void* d_out, int out_size, void* d_ws, size_t ws_size,
                              hipStream_t stream) {
    const float* X    = (const float*)d_in[0];
    const int*   ei   = (const int*)d_in[1];
    const float* attr = (const float*)d_in[2];
    const float* w_n1 = (const float*)d_in[3];
    const float* w_e1 = (const float*)d_in[4];
    const float* q1   = (const float*)d_in[5];
    const float* k1   = (const float*)d_in[6];
    const float* aw1  = (const float*)d_in[7];
    const float* ab1  = (const float*)d_in[8];
    const float* ow1  = (const float*)d_in[9];
    const float* ob1  = (const float*)d_in[10];
    const float* w_n2 = (const float*)d_in[11];
    const float* w_e2 = (const float*)d_in[12];
    const float* q2   = (const float*)d_in[13];
    const float* k2   = (const float*)d_in[14];
    const float* aw2  = (const float*)d_in[15];
    const float* ab2  = (const float*)d_in[16];
    const float* ow2  = (const float*)d_in[17];
    const float* ob2  = (const float*)d_in[18];
    float* out = (float*)d_out;

    char* ws = (char*)d_ws;
    float*  xpA    = (float*)(ws + OFF_XPA);
    float*  xpB    = (float*)(ws + OFF_XPB);
    float*  sa     = (float*)(ws + OFF_SA);
    float*  sb     = (float*)(ws + OFF_SB);
    float*  vecs   = (float*)(ws + OFF_VECS);
    int*    counts = (int*)(ws + OFF_COUNTS);
    int*    cursor = (int*)(ws + OFF_CURSOR);
    int*    offs   = (int*)(ws + OFF_OFFS);
    int2*   recs   = (int2*)(ws + OFF_RECS);
    float4* att    = (float4*)(ws + OFF_ATT);
    float2* se12   = (float2*)(ws + OFF_SE12);
    int*    order  = (int*)(ws + OFF_ORDER);

    // CSR build (edge_index is layer-invariant)
    hipMemsetAsync(counts, 0, 2 * NN * sizeof(int), stream);  // counts + cursor
    hist_vecs_kernel<<<EE / 256, 256, 0, stream>>>(ei, counts, q1, k1, aw1, w_e1,
                                                   q2, k2, aw2, w_e2, vecs);
    scan_order_kernel<<<1, 1024, 0, stream>>>(counts, offs, order);
    scatter_kernel<<<EE / 256, 256, 0, stream>>>(ei, offs, cursor, attr, vecs,
                                                 ab1, ab2, recs, se12);
    // layer 1
    node_prep_kernel<<<NN / 4, 256, 0, stream>>>(X, w_n1, vecs + 0, vecs + 64, xpA, sa, sb);
    att_kernel<<<EE / 256, 256, 0, stream>>>(ei, se12, sa, sb, att, 0);
    conv_out_kernel<<<NN / 4, 256, 0, stream>>>(xpA, recs, offs, attr, w_e1, att,
                                                ow1, ob1, order, xpB);
    // layer 2
    node_prep_kernel<<<NN / 4, 256, 0, stream>>>(xpB, w_n2, vecs + 144, vecs + 208, xpA, sa, sb);
    att_kernel<<<EE / 256, 256, 0, stream>>>(ei, se12, sa, sb, att, 1);
    conv_out_kernel<<<NN / 4, 256, 0, stream>>>(xpA, recs, offs, attr, w_e2, att,
                                                ow2, ob2, order, out);
}

// Round 8
// 273.801 us; speedup vs baseline: 1.0252x; 1.0252x over previous
//
#include <hip/hip_runtime.h>
#include <math.h>

#define NN 10000
#define BB 4
#define EE 160000
#define CC 64
#define CE 16

// ---- workspace layout (bytes) ----
static constexpr size_t OFF_XPA    = 0;          // float[NN*BB*CC]
static constexpr size_t OFF_XPB    = 10240000;   // float[NN*BB*CC]
static constexpr size_t OFF_SA     = 20480000;   // float[NN*BB]
static constexpr size_t OFF_SB     = 20640000;   // float[NN*BB]
static constexpr size_t OFF_VECS   = 20800000;   // float[288]
static constexpr size_t OFF_COUNTS = 20801280;   // int[NN]
static constexpr size_t OFF_CURSOR = 20841280;   // int[NN]
static constexpr size_t OFF_OFFS   = 20881280;   // int[NN+1]
static constexpr size_t OFF_RECS   = 20921344;   // int2[EE]   (1.28 MB)
static constexpr size_t OFF_ATT    = 22201344;   // float4[EE] (2.56 MB)
static constexpr size_t OFF_SE12   = 24761344;   // float2[EE] (1.28 MB)
static constexpr size_t OFF_ORDER  = 26041344;   // int[NN]    -> total ~26.1 MB

__device__ __forceinline__ float sigmoidf_(float x) {
    // v_rcp_f32 (~1ulp) instead of IEEE divide; validated absmax-identical r1-r7
    return __builtin_amdgcn_rcpf(1.0f + __expf(-x));
}

// broadcast lane `l` (compile-time) of v to all lanes via v_readlane (SGPR path,
// on the VALU pipes -- NOT the LDS pipe)
__device__ __forceinline__ float bcast_(float v, int l) {
    return __uint_as_float(__builtin_amdgcn_readlane(__float_as_uint(v), l));
}

// histogram of dst + (block 0) fold q@aw_q, k@aw_k, w_e@aw_e for both layers
__global__ void hist_vecs_kernel(const int* __restrict__ ei, int* __restrict__ counts,
                                 const float* __restrict__ q1, const float* __restrict__ k1,
                                 const float* __restrict__ aw1, const float* __restrict__ we1,
                                 const float* __restrict__ q2, const float* __restrict__ k2,
                                 const float* __restrict__ aw2, const float* __restrict__ we2,
                                 float* __restrict__ vecs) {
    int e = blockIdx.x * blockDim.x + threadIdx.x;
    if (e < EE) atomicAdd(&counts[ei[EE + e]], 1);
    if (blockIdx.x == 0) {
        int t = threadIdx.x;
        if (t < 64) {
            float a = 0.f, b = 0.f, c = 0.f, d = 0.f;
            for (int j = 0; j < 64; ++j) {
                a = fmaf(q1[t * 64 + j], aw1[j], a);
                b = fmaf(k1[t * 64 + j], aw1[64 + j], b);
                c = fmaf(q2[t * 64 + j], aw2[j], c);
                d = fmaf(k2[t * 64 + j], aw2[64 + j], d);
            }
            vecs[t] = a; vecs[64 + t] = b; vecs[144 + t] = c; vecs[208 + t] = d;
        }
        if (t < 16) {
            float a = 0.f, b = 0.f;
            for (int j = 0; j < 64; ++j) {
                a = fmaf(we1[t * 64 + j], aw1[128 + j], a);
                b = fmaf(we2[t * 64 + j], aw2[128 + j], b);
            }
            vecs[128 + t] = a; vecs[272 + t] = b;
        }
    }
}

// single-block: exclusive scan of counts -> offs, THEN counting-sort nodes by
// degree descending -> order[] (LPT schedule for conv_out).  r6 ATOMIC version:
// measured faster than the r7 ballot version by ~22 us (the ballot variant's
// 40 barriers + serial t<64 sections cost more than ~20k hot-bin LDS atomics
// overlapped across 16 waves).
__global__ __launch_bounds__(1024) void scan_order_kernel(const int* __restrict__ counts,
                                                          int* __restrict__ offs,
                                                          int* __restrict__ order) {
    __shared__ int hist[1024];
    __shared__ int cur[1024];
    __shared__ int startb[1024];
    __shared__ int wsum[16];
    int t = threadIdx.x;
    hist[t] = 0; cur[t] = 0;
    int lane = t & 63, wid = t >> 6;
    // ---- phase 1: exclusive scan ----
    int v[10];
    int s = 0;
    #pragma unroll
    for (int j = 0; j < 10; ++j) {
        int i = t * 10 + j;
        v[j] = (i < NN) ? counts[i] : 0;
        s += v[j];
    }
    int ps = s;
    #pragma unroll
    for (int off = 1; off < 64; off <<= 1) {
        int u = __shfl_up(ps, off, 64);
        if (lane >= off) ps += u;
    }
    if (lane == 63) wsum[wid] = ps;
    __syncthreads();   // also covers hist/cur zero-init
    int wbase = 0;
    for (int w = 0; w < wid; ++w) wbase += wsum[w];
    int tb = wbase + ps - s;  // exclusive prefix
    #pragma unroll
    for (int j = 0; j < 10; ++j) {
        int i = t * 10 + j;
        if (i < NN) offs[i] = tb;
        tb += v[j];
    }
    if (t == 1023) offs[NN] = tb;
    // ---- phase 2: degree histogram ----
    #pragma unroll
    for (int j = 0; j < 10; ++j) {
        int i = t * 10 + j;
        if (i < NN) {
            int d = v[j] > 1023 ? 1023 : v[j];
            atomicAdd(&hist[d], 1);
        }
    }
    __syncthreads();
    // ---- phase 3: suffix sums (descending bins) ----
    int r = 1023 - t;
    int hv = hist[r];
    int ps2 = hv;
    #pragma unroll
    for (int off = 1; off < 64; off <<= 1) {
        int u = __shfl_up(ps2, off, 64);
        if (lane >= off) ps2 += u;
    }
    if (lane == 63) wsum[wid] = ps2;
    __syncthreads();
    int wb2 = 0;
    for (int w = 0; w < wid; ++w) wb2 += wsum[w];
    startb[r] = wb2 + ps2 - hv;
    __syncthreads();
    // ---- phase 4: scatter node ids ----
    #pragma unroll
    for (int j = 0; j < 10; ++j) {
        int i = t * 10 + j;
        if (i < NN) {
            int d = v[j] > 1023 ? 1023 : v[j];
            int pos = startb[d] + atomicAdd(&cur[d], 1);
            order[pos] = i;
        }
    }
}

// CSR scatter; also fold attr·(w_e@aw_e)+ab per edge for both layers -> se12[e]
__global__ __launch_bounds__(256) void scatter_kernel(
    const int* __restrict__ ei, const int* __restrict__ offs,
    int* __restrict__ cursor, const float* __restrict__ attr,
    const float* __restrict__ vecs, const float* __restrict__ ab1,
    const float* __restrict__ ab2, int2* __restrict__ recs,
    float2* __restrict__ se12) {
    int e = blockIdx.x * blockDim.x + threadIdx.x;
    if (e >= EE) return;
    int s = ei[e], d = ei[EE + e];
    const float4* ap = (const float4*)(attr + (size_t)e * CE);
    float4 a0 = ap[0], a1 = ap[1], a2 = ap[2], a3 = ap[3];
    const float* v1 = vecs + 128;
    const float* v2 = vecs + 272;
    float s1 = ab1[0], s2 = ab2[0];
    s1 = fmaf(a0.x, v1[0], s1);  s1 = fmaf(a0.y, v1[1], s1);
    s1 = fmaf(a0.z, v1[2], s1);  s1 = fmaf(a0.w, v1[3], s1);
    s1 = fmaf(a1.x, v1[4], s1);  s1 = fmaf(a1.y, v1[5], s1);
    s1 = fmaf(a1.z, v1[6], s1);  s1 = fmaf(a1.w, v1[7], s1);
    s1 = fmaf(a2.x, v1[8], s1);  s1 = fmaf(a2.y, v1[9], s1);
    s1 = fmaf(a2.z, v1[10], s1); s1 = fmaf(a2.w, v1[11], s1);
    s1 = fmaf(a3.x, v1[12], s1); s1 = fmaf(a3.y, v1[13], s1);
    s1 = fmaf(a3.z, v1[14], s1); s1 = fmaf(a3.w, v1[15], s1);
    s2 = fmaf(a0.x, v2[0], s2);  s2 = fmaf(a0.y, v2[1], s2);
    s2 = fmaf(a0.z, v2[2], s2);  s2 = fmaf(a0.w, v2[3], s2);
    s2 = fmaf(a1.x, v2[4], s2);  s2 = fmaf(a1.y, v2[5], s2);
    s2 = fmaf(a1.z, v2[6], s2);  s2 = fmaf(a1.w, v2[7], s2);
    s2 = fmaf(a2.x, v2[8], s2);  s2 = fmaf(a2.y, v2[9], s2);
    s2 = fmaf(a2.z, v2[10], s2); s2 = fmaf(a2.w, v2[11], s2);
    s2 = fmaf(a3.x, v2[12], s2); s2 = fmaf(a3.y, v2[13], s2);
    s2 = fmaf(a3.z, v2[14], s2); s2 = fmaf(a3.w, v2[15], s2);
    int p = atomicAdd(&cursor[d], 1);
    recs[offs[d] + p] = make_int2(s, e);
    se12[e] = make_float2(s1, s2);
}

// xp = x @ w_n ; sa = xp@qa ; sb = xp@ka.  One wave per node, 4 nodes/block.
// ZERO LDS, ZERO barrier (r6-validated: -26 us non-conv): wave loads node row as
// one float4/lane; x[b][ci] broadcast via v_readlane at compile-time lane index.
__global__ __launch_bounds__(256) void node_prep_kernel(
    const float* __restrict__ x, const float* __restrict__ w_n,
    const float* __restrict__ qa, const float* __restrict__ ka,
    float* __restrict__ xp, float* __restrict__ sa, float* __restrict__ sb) {
    int t = threadIdx.x, wave = t >> 6, lane = t & 63;
    int node = blockIdx.x * 4 + wave;
    float4 xv = ((const float4*)(x + (size_t)node * BB * CC))[lane];
    float acc0 = 0.f, acc1 = 0.f, acc2 = 0.f, acc3 = 0.f;
    #pragma unroll
    for (int ci = 0; ci < 64; ++ci) {
        float w = w_n[ci * 64 + lane];                 // coalesced column of w_n
        float c0 = ((ci & 3) == 0) ? xv.x : ((ci & 3) == 1) ? xv.y
                 : ((ci & 3) == 2) ? xv.z : xv.w;
        int src = ci >> 2;
        acc0 = fmaf(bcast_(c0, (0 << 4) | src), w, acc0);
        acc1 = fmaf(bcast_(c0, (1 << 4) | src), w, acc1);
        acc2 = fmaf(bcast_(c0, (2 << 4) | src), w, acc2);
        acc3 = fmaf(bcast_(c0, (3 << 4) | src), w, acc3);
    }
    size_t obase = (size_t)node * BB * CC + lane;
    xp[obase] = acc0;
    xp[obase + 64] = acc1;
    xp[obase + 128] = acc2;
    xp[obase + 192] = acc3;
    float qv = qa[lane], kv = ka[lane];
    float ra0 = acc0 * qv, ra1 = acc1 * qv, ra2 = acc2 * qv, ra3 = acc3 * qv;
    float rb0 = acc0 * kv, rb1 = acc1 * kv, rb2 = acc2 * kv, rb3 = acc3 * kv;
    #pragma unroll
    for (int off = 32; off >= 1; off >>= 1) {
        ra0 += __shfl_xor(ra0, off, 64); ra1 += __shfl_xor(ra1, off, 64);
        ra2 += __shfl_xor(ra2, off, 64); ra3 += __shfl_xor(ra3, off, 64);
        rb0 += __shfl_xor(rb0, off, 64); rb1 += __shfl_xor(rb1, off, 64);
        rb2 += __shfl_xor(rb2, off, 64); rb3 += __shfl_xor(rb3, off, 64);
    }
    if (lane == 0) {
        sa[node * BB + 0] = ra0; sa[node * BB + 1] = ra1;
        sa[node * BB + 2] = ra2; sa[node * BB + 3] = ra3;
        sb[node * BB + 0] = rb0; sb[node * BB + 1] = rb1;
        sb[node * BB + 2] = rb2; sb[node * BB + 3] = rb3;
    }
}

// per-edge attention scalar: att4[e] = sigmoid(sa[src] + sb[dst] + se12[e])
__global__ __launch_bounds__(256) void att_kernel(
    const int* __restrict__ ei, const float2* __restrict__ se12,
    const float* __restrict__ sa, const float* __restrict__ sb,
    float4* __restrict__ att, int sel) {
    int e = blockIdx.x * blockDim.x + threadIdx.x;
    if (e >= EE) return;
    int s = ei[e], d = ei[EE + e];
    float2 se2 = se12[e];
    float se = sel ? se2.y : se2.x;
    float4 sas = *(const float4*)(sa + (size_t)s * BB);
    float4 sbn = *(const float4*)(sb + (size_t)d * BB);
    float4 r;
    r.x = sigmoidf_(sas.x + sbn.x + se);
    r.y = sigmoidf_(sas.y + sbn.y + se);
    r.z = sigmoidf_(sas.z + sbn.z + se);
    r.w = sigmoidf_(sas.w + sbn.w + se);
    att[e] = r;
}

// Per-node segment-max aggregation + output linear + residual + leaky_relu.
// r5/r7 form (54.5 us, reproduced twice): one wave per node (lane = channel),
// LPT order, simple 1-ahead rec prefetch (depth-2 regressed twice: r1, r6),
// readlane epilogue (zero LDS).
__global__ __launch_bounds__(256) void conv_out_kernel(
    const float* __restrict__ xp,      // [NN,BB,CC]
    const int2* __restrict__ recs,     // [EE] {src, e}
    const int* __restrict__ offs,      // [NN+1]
    const float* __restrict__ attr,    // [EE,CE]
    const float* __restrict__ w_e,     // [CE,CC]
    const float4* __restrict__ att,    // [EE]
    const float* __restrict__ ow,      // [2*CC,CC]
    const float* __restrict__ ob,      // [CC]
    const int* __restrict__ order,     // [NN] degree-descending node ids
    float* __restrict__ out) {         // [NN,BB,CC]
    int t = threadIdx.x;
    int wave = t >> 6, lane = t & 63;
    int node = order[blockIdx.x * 4 + wave];

    float wec[CE];
    #pragma unroll
    for (int j = 0; j < CE; ++j) wec[j] = w_e[j * CC + lane];

    const float* xn = xp + (size_t)node * BB * CC + lane;
    float xn0 = xn[0], xn1 = xn[64], xn2 = xn[128], xn3 = xn[192];

    int o0 = offs[node], o1 = offs[node + 1];
    float m0 = -INFINITY, m1 = -INFINITY, m2 = -INFINITY, m3 = -INFINITY;

    int i = o0;
    int2 rec = (i < o1) ? recs[i] : make_int2(0, 0);
    while (i < o1) {
        int2 cur = rec;
        ++i;
        if (i < o1) rec = recs[i];  // prefetch next
        int s = cur.x, e = cur.y;
        float4 at = att[e];
        const float4* ap = (const float4*)(attr + (size_t)e * CE);
        float4 a0 = ap[0], a1 = ap[1], a2 = ap[2], a3 = ap[3];
        float g = 0.f;
        g = fmaf(a0.x, wec[0], g);  g = fmaf(a0.y, wec[1], g);
        g = fmaf(a0.z, wec[2], g);  g = fmaf(a0.w, wec[3], g);
        g = fmaf(a1.x, wec[4], g);  g = fmaf(a1.y, wec[5], g);
        g = fmaf(a1.z, wec[6], g);  g = fmaf(a1.w, wec[7], g);
        g = fmaf(a2.x, wec[8], g);  g = fmaf(a2.y, wec[9], g);
        g = fmaf(a2.z, wec[10], g); g = fmaf(a2.w, wec[11], g);
        g = fmaf(a3.x, wec[12], g); g = fmaf(a3.y, wec[13], g);
        g = fmaf(a3.z, wec[14], g); g = fmaf(a3.w, wec[15], g);
        g = sigmoidf_(g);
        const float* xs = xp + (size_t)s * BB * CC + lane;
        float x0 = xs[0], x1 = xs[64], x2 = xs[128], x3 = xs[192];
        m0 = fmaxf(m0, at.x * x0 * g);
        m1 = fmaxf(m1, at.y * x1 * g);
        m2 = fmaxf(m2, at.z * x2 * g);
        m3 = fmaxf(m3, at.w * x3 * g);
    }
    // empty segments -> 0
    m0 = (m0 == -INFINITY) ? 0.f : m0;
    m1 = (m1 == -INFINITY) ? 0.f : m1;
    m2 = (m2 == -INFINITY) ? 0.f : m2;
    m3 = (m3 == -INFINITY) ? 0.f : m3;

    // ---- epilogue: out = xp + concat([xp, aggr]) @ ow + ob, leaky_relu ----
    // lane = output channel; per ci: 2 coalesced ow loads + 8 readlane + 8 FMA
    float o0f = 0.f, o1f = 0.f, o2f = 0.f, o3f = 0.f;
    #pragma unroll
    for (int ci = 0; ci < 64; ++ci) {
        float wa = ow[ci * 64 + lane];         // coalesced, L1/L2-resident
        float wb = ow[(64 + ci) * 64 + lane];
        o0f = fmaf(bcast_(xn0, ci), wa, o0f);
        o1f = fmaf(bcast_(xn1, ci), wa, o1f);
        o2f = fmaf(bcast_(xn2, ci), wa, o2f);
        o3f = fmaf(bcast_(xn3, ci), wa, o3f);
        o0f = fmaf(bcast_(m0, ci), wb, o0f);
        o1f = fmaf(bcast_(m1, ci), wb, o1f);
        o2f = fmaf(bcast_(m2, ci), wb, o2f);
        o3f = fmaf(bcast_(m3, ci), wb, o3f);
    }
    float obv = ob[lane];
    float r0 = xn0 + o0f + obv;
    float r1 = xn1 + o1f + obv;
    float r2 = xn2 + o2f + obv;
    float r3 = xn3 + o3f + obv;
    r0 = (r0 > 0.f) ? r0 : 0.01f * r0;
    r1 = (r1 > 0.f) ? r1 : 0.01f * r1;
    r2 = (r2 > 0.f) ? r2 : 0.01f * r2;
    r3 = (r3 > 0.f) ? r3 : 0.01f * r3;
    float* op = out + (size_t)node * BB * CC + lane;
    op[0] = r0; op[64] = r1; op[128] = r2; op[192] = r3;
}

extern "C" void kernel_launch(void* const* d_in, const int* in_sizes, int n_in,
                              void* d_out, int out_size, void* d_ws, size_t ws_size,
                              hipStream_t stream) {
    const float* X    = (const float*)d_in[0];
    const int*   ei   = (const int*)d_in[1];
    const float* attr = (const float*)d_in[2];
    const float* w_n1 = (const float*)d_in[3];
    const float* w_e1 = (const float*)d_in[4];
    const float* q1   = (const float*)d_in[5];
    const float* k1   = (const float*)d_in[6];
    const float* aw1  = (const float*)d_in[7];
    const float* ab1  = (const float*)d_in[8];
    const float* ow1  = (const float*)d_in[9];
    const float* ob1  = (const float*)d_in[10];
    const float* w_n2 = (const float*)d_in[11];
    const float* w_e2 = (const float*)d_in[12];
    const float* q2   = (const float*)d_in[13];
    const float* k2   = (const float*)d_in[14];
    const float* aw2  = (const float*)d_in[15];
    const float* ab2  = (const float*)d_in[16];
    const float* ow2  = (const float*)d_in[17];
    const float* ob2  = (const float*)d_in[18];
    float* out = (float*)d_out;

    char* ws = (char*)d_ws;
    float*  xpA    = (float*)(ws + OFF_XPA);
    float*  xpB    = (float*)(ws + OFF_XPB);
    float*  sa     = (float*)(ws + OFF_SA);
    float*  sb     = (float*)(ws + OFF_SB);
    float*  vecs   = (float*)(ws + OFF_VECS);
    int*    counts = (int*)(ws + OFF_COUNTS);
    int*    cursor = (int*)(ws + OFF_CURSOR);
    int*    offs   = (int*)(ws + OFF_OFFS);
    int2*   recs   = (int2*)(ws + OFF_RECS);
    float4* att    = (float4*)(ws + OFF_ATT);
    float2* se12   = (float2*)(ws + OFF_SE12);
    int*    order  = (int*)(ws + OFF_ORDER);

    // CSR build (edge_index is layer-invariant)
    hipMemsetAsync(counts, 0, 2 * NN * sizeof(int), stream);  // counts + cursor
    hist_vecs_kernel<<<EE / 256, 256, 0, stream>>>(ei, counts, q1, k1, aw1, w_e1,
                                                   q2, k2, aw2, w_e2, vecs);
    scan_order_kernel<<<1, 1024, 0, stream>>>(counts, offs, order);
    scatter_kernel<<<EE / 256, 256, 0, stream>>>(ei, offs, cursor, attr, vecs,
                                                 ab1, ab2, recs, se12);
    // layer 1
    node_prep_kernel<<<NN / 4, 256, 0, stream>>>(X, w_n1, vecs + 0, vecs + 64, xpA, sa, sb);
    att_kernel<<<EE / 256, 256, 0, stream>>>(ei, se12, sa, sb, att, 0);
    conv_out_kernel<<<NN / 4, 256, 0, stream>>>(xpA, recs, offs, attr, w_e1, att,
                                                ow1, ob1, order, xpB);
    // layer 2
    node_prep_kernel<<<NN / 4, 256, 0, stream>>>(xpB, w_n2, vecs + 144, vecs + 208, xpA, sa, sb);
    att_kernel<<<EE / 256, 256, 0, stream>>>(ei, se12, sa, sb, att, 1);
    conv_out_kernel<<<NN / 4, 256, 0, stream>>>(xpA, recs, offs, attr, w_e2, att,
                                                ow2, ob2, order, out);
}

// Round 9
// 270.864 us; speedup vs baseline: 1.0363x; 1.0108x over previous
//
#include <hip/hip_runtime.h>
#include <math.h>

#define NN 10000
#define BB 4
#define EE 160000
#define CC 64
#define CE 16

// ---- workspace layout (bytes) ----
static constexpr size_t OFF_XPA    = 0;          // float[NN*BB*CC]
static constexpr size_t OFF_XPB    = 10240000;   // float[NN*BB*CC]
static constexpr size_t OFF_SA     = 20480000;   // float[NN*BB]
static constexpr size_t OFF_SB     = 20640000;   // float[NN*BB]
static constexpr size_t OFF_VECS   = 20800000;   // float[288]
static constexpr size_t OFF_COUNTS = 20801280;   // int[NN]
static constexpr size_t OFF_CURSOR = 20841280;   // int[NN]
static constexpr size_t OFF_OFFS   = 20881280;   // int[NN+1]
static constexpr size_t OFF_RECS   = 20921344;   // int2[EE]   (1.28 MB)
static constexpr size_t OFF_ATT    = 22201344;   // float4[EE] (2.56 MB)
static constexpr size_t OFF_SE2    = 24761344;   // float[EE]  (0.64 MB)
static constexpr size_t OFF_ORDER  = 25401344;   // int[NN]    -> total ~25.4 MB

// Internal xp arrays use CHANNEL-MAJOR layout: xp[node][c][b], element (c,b) at
// node*256 + c*4 + b.  A wave (lane=channel) reads/writes a node row as ONE
// coalesced dwordx4 (1 KB) instead of 4 strided dword transactions.

__device__ __forceinline__ float sigmoidf_(float x) {
    // v_rcp_f32 (~1ulp) instead of IEEE divide; validated absmax-identical r1-r8
    return __builtin_amdgcn_rcpf(1.0f + __expf(-x));
}

// broadcast lane `l` (compile-time) of v to all lanes via v_readlane (SGPR path,
// on the VALU pipes -- NOT the LDS pipe)
__device__ __forceinline__ float bcast_(float v, int l) {
    return __uint_as_float(__builtin_amdgcn_readlane(__float_as_uint(v), l));
}

// histogram of dst + (block 0) fold q@aw_q, k@aw_k, w_e@aw_e for both layers
__global__ void hist_vecs_kernel(const int* __restrict__ ei, int* __restrict__ counts,
                                 const float* __restrict__ q1, const float* __restrict__ k1,
                                 const float* __restrict__ aw1, const float* __restrict__ we1,
                                 const float* __restrict__ q2, const float* __restrict__ k2,
                                 const float* __restrict__ aw2, const float* __restrict__ we2,
                                 float* __restrict__ vecs) {
    int e = blockIdx.x * blockDim.x + threadIdx.x;
    if (e < EE) atomicAdd(&counts[ei[EE + e]], 1);
    if (blockIdx.x == 0) {
        int t = threadIdx.x;
        if (t < 64) {
            float a = 0.f, b = 0.f, c = 0.f, d = 0.f;
            for (int j = 0; j < 64; ++j) {
                a = fmaf(q1[t * 64 + j], aw1[j], a);
                b = fmaf(k1[t * 64 + j], aw1[64 + j], b);
                c = fmaf(q2[t * 64 + j], aw2[j], c);
                d = fmaf(k2[t * 64 + j], aw2[64 + j], d);
            }
            vecs[t] = a; vecs[64 + t] = b; vecs[144 + t] = c; vecs[208 + t] = d;
        }
        if (t < 16) {
            float a = 0.f, b = 0.f;
            for (int j = 0; j < 64; ++j) {
                a = fmaf(we1[t * 64 + j], aw1[128 + j], a);
                b = fmaf(we2[t * 64 + j], aw2[128 + j], b);
            }
            vecs[128 + t] = a; vecs[272 + t] = b;
        }
    }
}

// single-block: exclusive scan of counts -> offs, THEN counting-sort nodes by
// degree descending -> order[].  r6/r8 atomic version (measured best).
__global__ __launch_bounds__(1024) void scan_order_kernel(const int* __restrict__ counts,
                                                          int* __restrict__ offs,
                                                          int* __restrict__ order) {
    __shared__ int hist[1024];
    __shared__ int cur[1024];
    __shared__ int startb[1024];
    __shared__ int wsum[16];
    int t = threadIdx.x;
    hist[t] = 0; cur[t] = 0;
    int lane = t & 63, wid = t >> 6;
    // ---- phase 1: exclusive scan ----
    int v[10];
    int s = 0;
    #pragma unroll
    for (int j = 0; j < 10; ++j) {
        int i = t * 10 + j;
        v[j] = (i < NN) ? counts[i] : 0;
        s += v[j];
    }
    int ps = s;
    #pragma unroll
    for (int off = 1; off < 64; off <<= 1) {
        int u = __shfl_up(ps, off, 64);
        if (lane >= off) ps += u;
    }
    if (lane == 63) wsum[wid] = ps;
    __syncthreads();   // also covers hist/cur zero-init
    int wbase = 0;
    for (int w = 0; w < wid; ++w) wbase += wsum[w];
    int tb = wbase + ps - s;  // exclusive prefix
    #pragma unroll
    for (int j = 0; j < 10; ++j) {
        int i = t * 10 + j;
        if (i < NN) offs[i] = tb;
        tb += v[j];
    }
    if (t == 1023) offs[NN] = tb;
    // ---- phase 2: degree histogram ----
    #pragma unroll
    for (int j = 0; j < 10; ++j) {
        int i = t * 10 + j;
        if (i < NN) {
            int d = v[j] > 1023 ? 1023 : v[j];
            atomicAdd(&hist[d], 1);
        }
    }
    __syncthreads();
    // ---- phase 3: suffix sums (descending bins) ----
    int r = 1023 - t;
    int hv = hist[r];
    int ps2 = hv;
    #pragma unroll
    for (int off = 1; off < 64; off <<= 1) {
        int u = __shfl_up(ps2, off, 64);
        if (lane >= off) ps2 += u;
    }
    if (lane == 63) wsum[wid] = ps2;
    __syncthreads();
    int wb2 = 0;
    for (int w = 0; w < wid; ++w) wb2 += wsum[w];
    startb[r] = wb2 + ps2 - hv;
    __syncthreads();
    // ---- phase 4: scatter node ids ----
    #pragma unroll
    for (int j = 0; j < 10; ++j) {
        int i = t * 10 + j;
        if (i < NN) {
            int d = v[j] > 1023 ? 1023 : v[j];
            int pos = startb[d] + atomicAdd(&cur[d], 1);
            order[pos] = i;
        }
    }
}

// xp = x @ w_n ; sa = xp@qa ; sb = xp@ka.  One wave per node, 4 nodes/block.
// ZERO LDS/barrier (r6-validated).  in_cm: input layout channel-major (layer 2)
// vs standard [B][C] (layer 1).  Output xp always channel-major, ONE dwordx4.
__global__ __launch_bounds__(256) void node_prep_kernel(
    const float* __restrict__ x, const float* __restrict__ w_n,
    const float* __restrict__ qa, const float* __restrict__ ka,
    float* __restrict__ xp, float* __restrict__ sa, float* __restrict__ sb,
    int in_cm) {
    int t = threadIdx.x, wave = t >> 6, lane = t & 63;
    int node = blockIdx.x * 4 + wave;
    float4 xv = ((const float4*)(x + (size_t)node * BB * CC))[lane];
    float acc0 = 0.f, acc1 = 0.f, acc2 = 0.f, acc3 = 0.f;
    if (in_cm) {
        // lane holds channel `lane`: (b0,b1,b2,b3).  x[b][ci] = comp b of lane ci.
        #pragma unroll
        for (int ci = 0; ci < 64; ++ci) {
            float w = w_n[ci * 64 + lane];
            acc0 = fmaf(bcast_(xv.x, ci), w, acc0);
            acc1 = fmaf(bcast_(xv.y, ci), w, acc1);
            acc2 = fmaf(bcast_(xv.z, ci), w, acc2);
            acc3 = fmaf(bcast_(xv.w, ci), w, acc3);
        }
    } else {
        // standard [B][C]: lane (b<<4)|q holds channels 4q..4q+3 of batch b
        #pragma unroll
        for (int ci = 0; ci < 64; ++ci) {
            float w = w_n[ci * 64 + lane];
            float c0 = ((ci & 3) == 0) ? xv.x : ((ci & 3) == 1) ? xv.y
                     : ((ci & 3) == 2) ? xv.z : xv.w;
            int src = ci >> 2;
            acc0 = fmaf(bcast_(c0, (0 << 4) | src), w, acc0);
            acc1 = fmaf(bcast_(c0, (1 << 4) | src), w, acc1);
            acc2 = fmaf(bcast_(c0, (2 << 4) | src), w, acc2);
            acc3 = fmaf(bcast_(c0, (3 << 4) | src), w, acc3);
        }
    }
    // channel-major store: one coalesced dwordx4 per lane
    ((float4*)(xp + (size_t)node * BB * CC))[lane] =
        make_float4(acc0, acc1, acc2, acc3);
    float qv = qa[lane], kv = ka[lane];
    float ra0 = acc0 * qv, ra1 = acc1 * qv, ra2 = acc2 * qv, ra3 = acc3 * qv;
    float rb0 = acc0 * kv, rb1 = acc1 * kv, rb2 = acc2 * kv, rb3 = acc3 * kv;
    #pragma unroll
    for (int off = 32; off >= 1; off >>= 1) {
        ra0 += __shfl_xor(ra0, off, 64); ra1 += __shfl_xor(ra1, off, 64);
        ra2 += __shfl_xor(ra2, off, 64); ra3 += __shfl_xor(ra3, off, 64);
        rb0 += __shfl_xor(rb0, off, 64); rb1 += __shfl_xor(rb1, off, 64);
        rb2 += __shfl_xor(rb2, off, 64); rb3 += __shfl_xor(rb3, off, 64);
    }
    if (lane == 0) {
        sa[node * BB + 0] = ra0; sa[node * BB + 1] = ra1;
        sa[node * BB + 2] = ra2; sa[node * BB + 3] = ra3;
        sb[node * BB + 0] = rb0; sb[node * BB + 1] = rb1;
        sb[node * BB + 2] = rb2; sb[node * BB + 3] = rb3;
    }
}

// CSR scatter + FUSED layer-1 attention (sa/sb available since node_prep1 runs
// first): recs, se2 (layer-2 scalar), att[e] = sigmoid(sa[s]+sb[d]+s1).
// Deletes the whole layer-1 att dispatch.
__global__ __launch_bounds__(256) void scatter_kernel(
    const int* __restrict__ ei, const int* __restrict__ offs,
    int* __restrict__ cursor, const float* __restrict__ attr,
    const float* __restrict__ vecs, const float* __restrict__ ab1,
    const float* __restrict__ ab2, const float* __restrict__ sa,
    const float* __restrict__ sb, int2* __restrict__ recs,
    float* __restrict__ se2, float4* __restrict__ att) {
    int e = blockIdx.x * blockDim.x + threadIdx.x;
    if (e >= EE) return;
    int s = ei[e], d = ei[EE + e];
    const float4* ap = (const float4*)(attr + (size_t)e * CE);
    float4 a0 = ap[0], a1 = ap[1], a2 = ap[2], a3 = ap[3];
    const float* v1 = vecs + 128;
    const float* v2 = vecs + 272;
    float s1 = ab1[0], s2 = ab2[0];
    s1 = fmaf(a0.x, v1[0], s1);  s1 = fmaf(a0.y, v1[1], s1);
    s1 = fmaf(a0.z, v1[2], s1);  s1 = fmaf(a0.w, v1[3], s1);
    s1 = fmaf(a1.x, v1[4], s1);  s1 = fmaf(a1.y, v1[5], s1);
    s1 = fmaf(a1.z, v1[6], s1);  s1 = fmaf(a1.w, v1[7], s1);
    s1 = fmaf(a2.x, v1[8], s1);  s1 = fmaf(a2.y, v1[9], s1);
    s1 = fmaf(a2.z, v1[10], s1); s1 = fmaf(a2.w, v1[11], s1);
    s1 = fmaf(a3.x, v1[12], s1); s1 = fmaf(a3.y, v1[13], s1);
    s1 = fmaf(a3.z, v1[14], s1); s1 = fmaf(a3.w, v1[15], s1);
    s2 = fmaf(a0.x, v2[0], s2);  s2 = fmaf(a0.y, v2[1], s2);
    s2 = fmaf(a0.z, v2[2], s2);  s2 = fmaf(a0.w, v2[3], s2);
    s2 = fmaf(a1.x, v2[4], s2);  s2 = fmaf(a1.y, v2[5], s2);
    s2 = fmaf(a1.z, v2[6], s2);  s2 = fmaf(a1.w, v2[7], s2);
    s2 = fmaf(a2.x, v2[8], s2);  s2 = fmaf(a2.y, v2[9], s2);
    s2 = fmaf(a2.z, v2[10], s2); s2 = fmaf(a2.w, v2[11], s2);
    s2 = fmaf(a3.x, v2[12], s2); s2 = fmaf(a3.y, v2[13], s2);
    s2 = fmaf(a3.z, v2[14], s2); s2 = fmaf(a3.w, v2[15], s2);
    int p = atomicAdd(&cursor[d], 1);
    recs[offs[d] + p] = make_int2(s, e);
    se2[e] = s2;
    float4 sas = *(const float4*)(sa + (size_t)s * BB);
    float4 sbn = *(const float4*)(sb + (size_t)d * BB);
    float4 r;
    r.x = sigmoidf_(sas.x + sbn.x + s1);
    r.y = sigmoidf_(sas.y + sbn.y + s1);
    r.z = sigmoidf_(sas.z + sbn.z + s1);
    r.w = sigmoidf_(sas.w + sbn.w + s1);
    att[e] = r;
}

// per-edge attention scalar, layer 2 only: att[e] = sigmoid(sa[s]+sb[d]+se2[e])
__global__ __launch_bounds__(256) void att_kernel(
    const int* __restrict__ ei, const float* __restrict__ se2,
    const float* __restrict__ sa, const float* __restrict__ sb,
    float4* __restrict__ att) {
    int e = blockIdx.x * blockDim.x + threadIdx.x;
    if (e >= EE) return;
    int s = ei[e], d = ei[EE + e];
    float se = se2[e];
    float4 sas = *(const float4*)(sa + (size_t)s * BB);
    float4 sbn = *(const float4*)(sb + (size_t)d * BB);
    float4 r;
    r.x = sigmoidf_(sas.x + sbn.x + se);
    r.y = sigmoidf_(sas.y + sbn.y + se);
    r.z = sigmoidf_(sas.z + sbn.z + se);
    r.w = sigmoidf_(sas.w + sbn.w + se);
    att[e] = r;
}

// Per-node segment-max aggregation + output linear + residual + leaky_relu.
// r5/r8 structure; xp now channel-major: the per-edge node-row gather is ONE
// coalesced dwordx4 (1 KB/wave) instead of 4 strided dword transactions.
// out_std: write standard [B][C] (final output, layer 2) vs channel-major.
__global__ __launch_bounds__(256) void conv_out_kernel(
    const float* __restrict__ xp,      // [NN][CC][BB] channel-major
    const int2* __restrict__ recs,     // [EE] {src, e}
    const int* __restrict__ offs,      // [NN+1]
    const float* __restrict__ attr,    // [EE,CE]
    const float* __restrict__ w_e,     // [CE,CC]
    const float4* __restrict__ att,    // [EE]
    const float* __restrict__ ow,      // [2*CC,CC]
    const float* __restrict__ ob,      // [CC]
    const int* __restrict__ order,     // [NN] degree-descending node ids
    float* __restrict__ out,           // layer1: CM; layer2: standard [B][C]
    int out_std) {
    int t = threadIdx.x;
    int wave = t >> 6, lane = t & 63;
    int node = order[blockIdx.x * 4 + wave];

    float wec[CE];
    #pragma unroll
    for (int j = 0; j < CE; ++j) wec[j] = w_e[j * CC + lane];

    float4 xnv = ((const float4*)(xp + (size_t)node * BB * CC))[lane];
    float xn0 = xnv.x, xn1 = xnv.y, xn2 = xnv.z, xn3 = xnv.w;

    int o0 = offs[node], o1 = offs[node + 1];
    float m0 = -INFINITY, m1 = -INFINITY, m2 = -INFINITY, m3 = -INFINITY;

    int i = o0;
    int2 rec = (i < o1) ? recs[i] : make_int2(0, 0);
    while (i < o1) {
        int2 cur = rec;
        ++i;
        if (i < o1) rec = recs[i];  // prefetch next
        int s = cur.x, e = cur.y;
        float4 at = att[e];
        const float4* ap = (const float4*)(attr + (size_t)e * CE);
        float4 a0 = ap[0], a1 = ap[1], a2 = ap[2], a3 = ap[3];
        float g = 0.f;
        g = fmaf(a0.x, wec[0], g);  g = fmaf(a0.y, wec[1], g);
        g = fmaf(a0.z, wec[2], g);  g = fmaf(a0.w, wec[3], g);
        g = fmaf(a1.x, wec[4], g);  g = fmaf(a1.y, wec[5], g);
        g = fmaf(a1.z, wec[6], g);  g = fmaf(a1.w, wec[7], g);
        g = fmaf(a2.x, wec[8], g);  g = fmaf(a2.y, wec[9], g);
        g = fmaf(a2.z, wec[10], g); g = fmaf(a2.w, wec[11], g);
        g = fmaf(a3.x, wec[12], g); g = fmaf(a3.y, wec[13], g);
        g = fmaf(a3.z, wec[14], g); g = fmaf(a3.w, wec[15], g);
        g = sigmoidf_(g);
        float4 xv4 = ((const float4*)(xp + (size_t)s * BB * CC))[lane];  // 1 coalesced dwordx4
        m0 = fmaxf(m0, at.x * xv4.x * g);
        m1 = fmaxf(m1, at.y * xv4.y * g);
        m2 = fmaxf(m2, at.z * xv4.z * g);
        m3 = fmaxf(m3, at.w * xv4.w * g);
    }
    // empty segments -> 0
    m0 = (m0 == -INFINITY) ? 0.f : m0;
    m1 = (m1 == -INFINITY) ? 0.f : m1;
    m2 = (m2 == -INFINITY) ? 0.f : m2;
    m3 = (m3 == -INFINITY) ? 0.f : m3;

    // ---- epilogue: out = xp + concat([xp, aggr]) @ ow + ob, leaky_relu ----
    // lane = output channel; per ci: 2 coalesced ow loads + 8 readlane + 8 FMA
    float o0f = 0.f, o1f = 0.f, o2f = 0.f, o3f = 0.f;
    #pragma unroll
    for (int ci = 0; ci < 64; ++ci) {
        float wa = ow[ci * 64 + lane];         // coalesced, L1/L2-resident
        float wb = ow[(64 + ci) * 64 + lane];
        o0f = fmaf(bcast_(xn0, ci), wa, o0f);
        o1f = fmaf(bcast_(xn1, ci), wa, o1f);
        o2f = fmaf(bcast_(xn2, ci), wa, o2f);
        o3f = fmaf(bcast_(xn3, ci), wa, o3f);
        o0f = fmaf(bcast_(m0, ci), wb, o0f);
        o1f = fmaf(bcast_(m1, ci), wb, o1f);
        o2f = fmaf(bcast_(m2, ci), wb, o2f);
        o3f = fmaf(bcast_(m3, ci), wb, o3f);
    }
    float obv = ob[lane];
    float r0 = xn0 + o0f + obv;
    float r1 = xn1 + o1f + obv;
    float r2 = xn2 + o2f + obv;
    float r3 = xn3 + o3f + obv;
    r0 = (r0 > 0.f) ? r0 : 0.01f * r0;
    r1 = (r1 > 0.f) ? r1 : 0.01f * r1;
    r2 = (r2 > 0.f) ? r2 : 0.01f * r2;
    r3 = (r3 > 0.f) ? r3 : 0.01f * r3;
    if (out_std) {
        float* op = out + (size_t)node * BB * CC + lane;   // standard [B][C]
        op[0] = r0; op[64] = r1; op[128] = r2; op[192] = r3;
    } else {
        ((float4*)(out + (size_t)node * BB * CC))[lane] =  // channel-major
            make_float4(r0, r1, r2, r3);
    }
}

extern "C" void kernel_launch(void* const* d_in, const int* in_sizes, int n_in,
                              void* d_out, int out_size, void* d_ws, size_t ws_size,
                              hipStream_t stream) {
    const float* X    = (const float*)d_in[0];
    const int*   ei   = (const int*)d_in[1];
    const float* attr = (const float*)d_in[2];
    const float* w_n1 = (const float*)d_in[3];
    const float* w_e1 = (const float*)d_in[4];
    const float* q1   = (const float*)d_in[5];
    const float* k1   = (const float*)d_in[6];
    const float* aw1  = (const float*)d_in[7];
    const float* ab1  = (const float*)d_in[8];
    const float* ow1  = (const float*)d_in[9];
    const float* ob1  = (const float*)d_in[10];
    const float* w_n2 = (const float*)d_in[11];
    const float* w_e2 = (const float*)d_in[12];
    const float* q2   = (const float*)d_in[13];
    const float* k2   = (const float*)d_in[14];
    const float* aw2  = (const float*)d_in[15];
    const float* ab2  = (const float*)d_in[16];
    const float* ow2  = (const float*)d_in[17];
    const float* ob2  = (const float*)d_in[18];
    float* out = (float*)d_out;

    char* ws = (char*)d_ws;
    float*  xpA    = (float*)(ws + OFF_XPA);
    float*  xpB    = (float*)(ws + OFF_XPB);
    float*  sa     = (float*)(ws + OFF_SA);
    float*  sb     = (float*)(ws + OFF_SB);
    float*  vecs   = (float*)(ws + OFF_VECS);
    int*    counts = (int*)(ws + OFF_COUNTS);
    int*    cursor = (int*)(ws + OFF_CURSOR);
    int*    offs   = (int*)(ws + OFF_OFFS);
    int2*   recs   = (int2*)(ws + OFF_RECS);
    float4* att    = (float4*)(ws + OFF_ATT);
    float*  se2    = (float*)(ws + OFF_SE2);
    int*    order  = (int*)(ws + OFF_ORDER);

    // CSR build (edge_index is layer-invariant)
    hipMemsetAsync(counts, 0, 2 * NN * sizeof(int), stream);  // counts + cursor
    hist_vecs_kernel<<<EE / 256, 256, 0, stream>>>(ei, counts, q1, k1, aw1, w_e1,
                                                   q2, k2, aw2, w_e2, vecs);
    // node_prep1 before scatter so layer-1 attention fuses into scatter
    node_prep_kernel<<<NN / 4, 256, 0, stream>>>(X, w_n1, vecs + 0, vecs + 64,
                                                 xpA, sa, sb, 0);
    scan_order_kernel<<<1, 1024, 0, stream>>>(counts, offs, order);
    scatter_kernel<<<EE / 256, 256, 0, stream>>>(ei, offs, cursor, attr, vecs,
                                                 ab1, ab2, sa, sb, recs, se2, att);
    // layer 1
    conv_out_kernel<<<NN / 4, 256, 0, stream>>>(xpA, recs, offs, attr, w_e1, att,
                                                ow1, ob1, order, xpB, 0);
    // layer 2
    node_prep_kernel<<<NN / 4, 256, 0, stream>>>(xpB, w_n2, vecs + 144, vecs + 208,
                                                 xpA, sa, sb, 1);
    att_kernel<<<EE / 256, 256, 0, stream>>>(ei, se2, sa, sb, att);
    conv_out_kernel<<<NN / 4, 256, 0, stream>>>(xpA, recs, offs, attr, w_e2, att,
                                                ow2, ob2, order, out, 1);
}